// Round 1
// baseline (2457.702 us; speedup 1.0000x reference)
//
#include <hip/hip_runtime.h>
#include <cstddef>

#define NN 50000
#define NE 800000
#define HC 128
#define OC 64
#define NL 3
#define BN_EPS 1e-5f

__global__ void init_deg(int* __restrict__ deg) {
    int i = blockIdx.x * blockDim.x + threadIdx.x;
    if (i < NN) deg[i] = 1;  // self-loop
}

__global__ void count_deg(const int* __restrict__ dst, int* __restrict__ deg) {
    int e = blockIdx.x * blockDim.x + threadIdx.x;
    if (e < NE) atomicAdd(&deg[dst[e]], 1);
}

__global__ void calc_dinv(const int* __restrict__ deg, float* __restrict__ dinv) {
    int i = blockIdx.x * blockDim.x + threadIdx.x;
    if (i < NN) dinv[i] = rsqrtf((float)deg[i]);
}

// 512 threads, 64 rows/block. Each thread: 16 cols of BOTH x@Wg and x@Wl.
// Writes h = x@Wg and xnext = x@Wl + bl + bg + dinv^2 * h (self-loop folded in).
__global__ __launch_bounds__(512) void gemm_dual(
    const float* __restrict__ xin,
    const float* __restrict__ Wg, const float* __restrict__ Wl,
    const float* __restrict__ bg, const float* __restrict__ bl,
    const float* __restrict__ dinv,
    float* __restrict__ hbuf, float* __restrict__ xnext)
{
    __shared__ float sWg[HC * HC];
    __shared__ float sWl[HC * HC];
    const int t = threadIdx.x;
    for (int i = t; i < HC * HC / 4; i += 512) {
        reinterpret_cast<float4*>(sWg)[i] = reinterpret_cast<const float4*>(Wg)[i];
        reinterpret_cast<float4*>(sWl)[i] = reinterpret_cast<const float4*>(Wl)[i];
    }
    __syncthreads();
    const int row = blockIdx.x * 64 + (t >> 3);
    if (row >= NN) return;
    const int c0 = (t & 7) * 16;

    float accG[16], accL[16];
#pragma unroll
    for (int j = 0; j < 16; ++j) { accG[j] = 0.f; accL[j] = 0.f; }

    const float4* xr4 = reinterpret_cast<const float4*>(xin + (size_t)row * HC);
#pragma unroll 4
    for (int k4 = 0; k4 < HC / 4; ++k4) {
        const float4 xv = xr4[k4];
        const float xs[4] = {xv.x, xv.y, xv.z, xv.w};
#pragma unroll
        for (int kk = 0; kk < 4; ++kk) {
            const int k = k4 * 4 + kk;
            const float4* wg = reinterpret_cast<const float4*>(sWg + k * HC + c0);
            const float4* wl = reinterpret_cast<const float4*>(sWl + k * HC + c0);
#pragma unroll
            for (int jj = 0; jj < 4; ++jj) {
                const float4 g = wg[jj], l = wl[jj];
                accG[4 * jj + 0] += xs[kk] * g.x;
                accG[4 * jj + 1] += xs[kk] * g.y;
                accG[4 * jj + 2] += xs[kk] * g.z;
                accG[4 * jj + 3] += xs[kk] * g.w;
                accL[4 * jj + 0] += xs[kk] * l.x;
                accL[4 * jj + 1] += xs[kk] * l.y;
                accL[4 * jj + 2] += xs[kk] * l.z;
                accL[4 * jj + 3] += xs[kk] * l.w;
            }
        }
    }

    const float dv = dinv[row];
    const float selfn = dv * dv;
    float* hp = hbuf + (size_t)row * HC + c0;
    float* xp = xnext + (size_t)row * HC + c0;
#pragma unroll
    for (int jj = 0; jj < 4; ++jj) {
        float4 ho, xo;
        float* hg = &accG[4 * jj];
        float* xl = &accL[4 * jj];
        ho.x = hg[0]; ho.y = hg[1]; ho.z = hg[2]; ho.w = hg[3];
        xo.x = xl[0] + bl[c0 + 4 * jj + 0] + bg[c0 + 4 * jj + 0] + selfn * hg[0];
        xo.y = xl[1] + bl[c0 + 4 * jj + 1] + bg[c0 + 4 * jj + 1] + selfn * hg[1];
        xo.z = xl[2] + bl[c0 + 4 * jj + 2] + bg[c0 + 4 * jj + 2] + selfn * hg[2];
        xo.w = xl[3] + bl[c0 + 4 * jj + 3] + bg[c0 + 4 * jj + 3] + selfn * hg[3];
        reinterpret_cast<float4*>(hp)[jj] = ho;
        reinterpret_cast<float4*>(xp)[jj] = xo;
    }
}

// 64 lanes per edge, 2 channels per lane (float2), atomic accumulate into xnext[dst].
__global__ void scatter_edges(
    const int* __restrict__ src, const int* __restrict__ dst,
    const float* __restrict__ dinv, const float* __restrict__ h,
    float* __restrict__ xnext)
{
    const long long tid = (long long)blockIdx.x * blockDim.x + threadIdx.x;
    const int e = (int)(tid >> 6);
    const int lane = (int)(tid & 63);
    if (e >= NE) return;
    const int s = src[e];
    const int d = dst[e];
    const float nrm = dinv[s] * dinv[d];
    const float2 hv = reinterpret_cast<const float2*>(h + (size_t)s * HC)[lane];
    float* outp = xnext + (size_t)d * HC + 2 * lane;
    atomicAdd(outp, hv.x * nrm);
    atomicAdd(outp + 1, hv.y * nrm);
}

// In-place BN (eval) + ReLU, vectorized float4.
__global__ void bn_relu(
    float* __restrict__ x,
    const float* __restrict__ g, const float* __restrict__ b,
    const float* __restrict__ rm, const float* __restrict__ rv)
{
    const int i = blockIdx.x * blockDim.x + threadIdx.x;
    if (i >= NN * HC / 4) return;
    const int c4 = i & (HC / 4 - 1);
    const float4 gv = reinterpret_cast<const float4*>(g)[c4];
    const float4 bv = reinterpret_cast<const float4*>(b)[c4];
    const float4 mv = reinterpret_cast<const float4*>(rm)[c4];
    const float4 vv = reinterpret_cast<const float4*>(rv)[c4];
    float4 v = reinterpret_cast<float4*>(x)[i];
    v.x = fmaxf((v.x - mv.x) * rsqrtf(vv.x + BN_EPS) * gv.x + bv.x, 0.f);
    v.y = fmaxf((v.y - mv.y) * rsqrtf(vv.y + BN_EPS) * gv.y + bv.y, 0.f);
    v.z = fmaxf((v.z - mv.z) * rsqrtf(vv.z + BN_EPS) * gv.z + bv.z, 0.f);
    v.w = fmaxf((v.w - mv.w) * rsqrtf(vv.w + BN_EPS) * gv.w + bv.w, 0.f);
    reinterpret_cast<float4*>(x)[i] = v;
}

// out[N,64] = x @ Wp + bp.  256 threads, 64 rows/block, 16 cols/thread.
__global__ __launch_bounds__(256) void gemm_out(
    const float* __restrict__ xin, const float* __restrict__ Wp,
    const float* __restrict__ bp, float* __restrict__ out)
{
    __shared__ float sW[HC * OC];
    const int t = threadIdx.x;
    for (int i = t; i < HC * OC / 4; i += 256)
        reinterpret_cast<float4*>(sW)[i] = reinterpret_cast<const float4*>(Wp)[i];
    __syncthreads();
    const int row = blockIdx.x * 64 + (t >> 2);
    if (row >= NN) return;
    const int c0 = (t & 3) * 16;

    float acc[16];
#pragma unroll
    for (int j = 0; j < 16; ++j) acc[j] = 0.f;

    const float4* xr4 = reinterpret_cast<const float4*>(xin + (size_t)row * HC);
#pragma unroll 4
    for (int k4 = 0; k4 < HC / 4; ++k4) {
        const float4 xv = xr4[k4];
        const float xs[4] = {xv.x, xv.y, xv.z, xv.w};
#pragma unroll
        for (int kk = 0; kk < 4; ++kk) {
            const int k = k4 * 4 + kk;
            const float4* w = reinterpret_cast<const float4*>(sW + k * OC + c0);
#pragma unroll
            for (int jj = 0; jj < 4; ++jj) {
                const float4 wv = w[jj];
                acc[4 * jj + 0] += xs[kk] * wv.x;
                acc[4 * jj + 1] += xs[kk] * wv.y;
                acc[4 * jj + 2] += xs[kk] * wv.z;
                acc[4 * jj + 3] += xs[kk] * wv.w;
            }
        }
    }
    float* op = out + (size_t)row * OC + c0;
#pragma unroll
    for (int jj = 0; jj < 4; ++jj) {
        float4 o;
        o.x = acc[4 * jj + 0] + bp[c0 + 4 * jj + 0];
        o.y = acc[4 * jj + 1] + bp[c0 + 4 * jj + 1];
        o.z = acc[4 * jj + 2] + bp[c0 + 4 * jj + 2];
        o.w = acc[4 * jj + 3] + bp[c0 + 4 * jj + 3];
        reinterpret_cast<float4*>(op)[jj] = o;
    }
}

extern "C" void kernel_launch(void* const* d_in, const int* in_sizes, int n_in,
                              void* d_out, int out_size, void* d_ws, size_t ws_size,
                              hipStream_t stream) {
    const float* x    = (const float*)d_in[0];
    const int*   ei   = (const int*)d_in[1];      // [2,E] int32
    const float* Wg   = (const float*)d_in[2];    // [L,H,H]
    const float* bg   = (const float*)d_in[3];    // [L,H]
    const float* Wl   = (const float*)d_in[4];
    const float* bl   = (const float*)d_in[5];
    const float* bn_g = (const float*)d_in[6];
    const float* bn_b = (const float*)d_in[7];
    const float* bn_rm= (const float*)d_in[8];
    const float* bn_rv= (const float*)d_in[9];
    const float* Wp   = (const float*)d_in[10];
    const float* bp   = (const float*)d_in[11];
    float* out = (float*)d_out;

    const int* e_src = ei;
    const int* e_dst = ei + NE;

    float* bufA = (float*)d_ws;                 // N*H
    float* bufB = bufA + (size_t)NN * HC;       // N*H
    float* bufH = bufB + (size_t)NN * HC;       // N*H
    float* dinv = bufH + (size_t)NN * HC;       // N
    int*   deg  = (int*)(dinv + NN);            // N

    // degree + dinv (once)
    init_deg<<<(NN + 255) / 256, 256, 0, stream>>>(deg);
    count_deg<<<(NE + 255) / 256, 256, 0, stream>>>(e_dst, deg);
    calc_dinv<<<(NN + 255) / 256, 256, 0, stream>>>(deg, dinv);

    const int gemm_blocks = (NN + 63) / 64;
    const int scat_blocks = (int)(((long long)NE * 64 + 255) / 256);
    const int bn_blocks = (NN * HC / 4 + 255) / 256;

    const float* xin = x;
    float* pp[NL] = {bufA, bufB, bufA};  // layer output buffers
    for (int l = 0; l < NL; ++l) {
        float* xnext = pp[l];
        gemm_dual<<<gemm_blocks, 512, 0, stream>>>(
            xin, Wg + (size_t)l * HC * HC, Wl + (size_t)l * HC * HC,
            bg + (size_t)l * HC, bl + (size_t)l * HC, dinv, bufH, xnext);
        scatter_edges<<<scat_blocks, 256, 0, stream>>>(e_src, e_dst, dinv, bufH, xnext);
        bn_relu<<<bn_blocks, 256, 0, stream>>>(
            xnext, bn_g + (size_t)l * HC, bn_b + (size_t)l * HC,
            bn_rm + (size_t)l * HC, bn_rv + (size_t)l * HC);
        xin = xnext;
    }

    gemm_out<<<gemm_blocks, 256, 0, stream>>>(xin, Wp, bp, out);
}

// Round 2
// 696.842 us; speedup vs baseline: 3.5269x; 3.5269x over previous
//
#include <hip/hip_runtime.h>
#include <cstddef>

#define NN 50000
#define NE 800000
#define HC 128
#define OC 64
#define NL 3
#define BN_EPS 1e-5f
#define NB ((NN + 1023) / 1024)   // scan blocks (1024 elems each) = 49

// ---------------- degree / dinv ----------------
__global__ void init_cnt(int* __restrict__ cnt) {
    int i = blockIdx.x * blockDim.x + threadIdx.x;
    if (i < NN) cnt[i] = 0;
}

__global__ void count_deg(const int* __restrict__ dst, int* __restrict__ cnt) {
    int e = blockIdx.x * blockDim.x + threadIdx.x;
    if (e < NE) atomicAdd(&cnt[dst[e]], 1);
}

__global__ void calc_dinv(const int* __restrict__ cnt, float* __restrict__ dinv) {
    int i = blockIdx.x * blockDim.x + threadIdx.x;
    if (i < NN) dinv[i] = rsqrtf((float)(cnt[i] + 1));   // +1 self-loop
}

// ---------------- exclusive scan (3 kernels) ----------------
__global__ __launch_bounds__(256) void scan1(const int* __restrict__ cnt,
                                             int* __restrict__ offs,
                                             int* __restrict__ partials) {
    __shared__ int sm[256];
    const int t = threadIdx.x;
    const int base = blockIdx.x * 1024 + t * 4;
    int c[4];
#pragma unroll
    for (int k = 0; k < 4; ++k) c[k] = (base + k < NN) ? cnt[base + k] : 0;
    int s = c[0] + c[1] + c[2] + c[3];
    sm[t] = s;
    __syncthreads();
    for (int off = 1; off < 256; off <<= 1) {
        int v = (t >= off) ? sm[t - off] : 0;
        __syncthreads();
        sm[t] += v;
        __syncthreads();
    }
    int run = sm[t] - s;   // exclusive
    if (t == 255) partials[blockIdx.x] = sm[255];
#pragma unroll
    for (int k = 0; k < 4; ++k) {
        if (base + k < NN) { offs[base + k] = run; run += c[k]; }
    }
}

__global__ void scan2(int* __restrict__ partials) {
    if (threadIdx.x == 0) {
        int run = 0;
        for (int i = 0; i < NB; ++i) { int v = partials[i]; partials[i] = run; run += v; }
    }
}

__global__ void scan3(int* __restrict__ offs, const int* __restrict__ partials,
                      int* __restrict__ cursor) {
    int i = blockIdx.x * blockDim.x + threadIdx.x;
    if (i < NN) { offs[i] += partials[i >> 10]; cursor[i] = 0; }
}

// ---------------- CSR fill ----------------
__global__ void fill_csr(const int* __restrict__ src, const int* __restrict__ dst,
                         const float* __restrict__ dinv, const int* __restrict__ offs,
                         int* __restrict__ cursor,
                         int* __restrict__ csr_src, float* __restrict__ csr_w) {
    int e = blockIdx.x * blockDim.x + threadIdx.x;
    if (e >= NE) return;
    int s = src[e], d = dst[e];
    int p = offs[d] + atomicAdd(&cursor[d], 1);
    csr_src[p] = s;
    csr_w[p] = dinv[s] * dinv[d];
}

// ---------------- fused dual GEMM (x@Wg -> h ; x@Wl + biases + self-loop -> xnext) ----------------
__global__ __launch_bounds__(512) void gemm_dual(
    const float* __restrict__ xin,
    const float* __restrict__ Wg, const float* __restrict__ Wl,
    const float* __restrict__ bg, const float* __restrict__ bl,
    const float* __restrict__ dinv,
    float* __restrict__ hbuf, float* __restrict__ xnext)
{
    __shared__ float sWg[HC * HC];
    __shared__ float sWl[HC * HC];
    const int t = threadIdx.x;
    for (int i = t; i < HC * HC / 4; i += 512) {
        reinterpret_cast<float4*>(sWg)[i] = reinterpret_cast<const float4*>(Wg)[i];
        reinterpret_cast<float4*>(sWl)[i] = reinterpret_cast<const float4*>(Wl)[i];
    }
    __syncthreads();
    const int row = blockIdx.x * 64 + (t >> 3);
    if (row >= NN) return;
    const int c0 = (t & 7) * 16;

    float accG[16], accL[16];
#pragma unroll
    for (int j = 0; j < 16; ++j) { accG[j] = 0.f; accL[j] = 0.f; }

    const float4* xr4 = reinterpret_cast<const float4*>(xin + (size_t)row * HC);
#pragma unroll 4
    for (int k4 = 0; k4 < HC / 4; ++k4) {
        const float4 xv = xr4[k4];
        const float xs[4] = {xv.x, xv.y, xv.z, xv.w};
#pragma unroll
        for (int kk = 0; kk < 4; ++kk) {
            const int k = k4 * 4 + kk;
            const float4* wg = reinterpret_cast<const float4*>(sWg + k * HC + c0);
            const float4* wl = reinterpret_cast<const float4*>(sWl + k * HC + c0);
#pragma unroll
            for (int jj = 0; jj < 4; ++jj) {
                const float4 g = wg[jj], l = wl[jj];
                accG[4 * jj + 0] += xs[kk] * g.x;
                accG[4 * jj + 1] += xs[kk] * g.y;
                accG[4 * jj + 2] += xs[kk] * g.z;
                accG[4 * jj + 3] += xs[kk] * g.w;
                accL[4 * jj + 0] += xs[kk] * l.x;
                accL[4 * jj + 1] += xs[kk] * l.y;
                accL[4 * jj + 2] += xs[kk] * l.z;
                accL[4 * jj + 3] += xs[kk] * l.w;
            }
        }
    }

    const float dv = dinv[row];
    const float selfn = dv * dv;
    float* hp = hbuf + (size_t)row * HC + c0;
    float* xp = xnext + (size_t)row * HC + c0;
#pragma unroll
    for (int jj = 0; jj < 4; ++jj) {
        float4 ho, xo;
        float* hg = &accG[4 * jj];
        float* xl = &accL[4 * jj];
        ho.x = hg[0]; ho.y = hg[1]; ho.z = hg[2]; ho.w = hg[3];
        xo.x = xl[0] + bl[c0 + 4 * jj + 0] + bg[c0 + 4 * jj + 0] + selfn * hg[0];
        xo.y = xl[1] + bl[c0 + 4 * jj + 1] + bg[c0 + 4 * jj + 1] + selfn * hg[1];
        xo.z = xl[2] + bl[c0 + 4 * jj + 2] + bg[c0 + 4 * jj + 2] + selfn * hg[2];
        xo.w = xl[3] + bl[c0 + 4 * jj + 3] + bg[c0 + 4 * jj + 3] + selfn * hg[3];
        reinterpret_cast<float4*>(hp)[jj] = ho;
        reinterpret_cast<float4*>(xp)[jj] = xo;
    }
}

// ---------------- CSR gather + BN + ReLU (replaces scatter + bn_relu) ----------------
// Half-wave (32 lanes) per node, float4 per lane = 128 channels.
// xio already holds x@Wl + bl + bg + selfloop; we add the neighbor sum, then BN+ReLU.
__global__ __launch_bounds__(256) void gather_conv_bn(
    const int* __restrict__ csr_src, const float* __restrict__ csr_w,
    const int* __restrict__ offs, const int* __restrict__ cnt,
    const float* __restrict__ h, float* __restrict__ xio,
    const float* __restrict__ g, const float* __restrict__ bb,
    const float* __restrict__ rm, const float* __restrict__ rv)
{
    const int widx = threadIdx.x >> 6;
    const int lane = threadIdx.x & 63;
    const int half = lane >> 5;
    const int li = lane & 31;
    const int node = blockIdx.x * 8 + widx * 2 + half;
    if (node >= NN) return;
    const int beg = offs[node];
    const int n = cnt[node];

    float4 acc = {0.f, 0.f, 0.f, 0.f};
    int j = 0;
    for (; j + 2 <= n; j += 2) {
        const int s0 = csr_src[beg + j];
        const int s1 = csr_src[beg + j + 1];
        const float w0 = csr_w[beg + j];
        const float w1 = csr_w[beg + j + 1];
        const float4 h0 = reinterpret_cast<const float4*>(h + (size_t)s0 * HC)[li];
        const float4 h1 = reinterpret_cast<const float4*>(h + (size_t)s1 * HC)[li];
        acc.x += w0 * h0.x + w1 * h1.x;
        acc.y += w0 * h0.y + w1 * h1.y;
        acc.z += w0 * h0.z + w1 * h1.z;
        acc.w += w0 * h0.w + w1 * h1.w;
    }
    if (j < n) {
        const int s0 = csr_src[beg + j];
        const float w0 = csr_w[beg + j];
        const float4 h0 = reinterpret_cast<const float4*>(h + (size_t)s0 * HC)[li];
        acc.x += w0 * h0.x;
        acc.y += w0 * h0.y;
        acc.z += w0 * h0.z;
        acc.w += w0 * h0.w;
    }

    float4 xv = reinterpret_cast<float4*>(xio + (size_t)node * HC)[li];
    xv.x += acc.x; xv.y += acc.y; xv.z += acc.z; xv.w += acc.w;

    const float4 gv = reinterpret_cast<const float4*>(g)[li];
    const float4 bv = reinterpret_cast<const float4*>(bb)[li];
    const float4 mv = reinterpret_cast<const float4*>(rm)[li];
    const float4 vv = reinterpret_cast<const float4*>(rv)[li];
    xv.x = fmaxf((xv.x - mv.x) * rsqrtf(vv.x + BN_EPS) * gv.x + bv.x, 0.f);
    xv.y = fmaxf((xv.y - mv.y) * rsqrtf(vv.y + BN_EPS) * gv.y + bv.y, 0.f);
    xv.z = fmaxf((xv.z - mv.z) * rsqrtf(vv.z + BN_EPS) * gv.z + bv.z, 0.f);
    xv.w = fmaxf((xv.w - mv.w) * rsqrtf(vv.w + BN_EPS) * gv.w + bv.w, 0.f);
    reinterpret_cast<float4*>(xio + (size_t)node * HC)[li] = xv;
}

// ---------------- output projection ----------------
__global__ __launch_bounds__(256) void gemm_out(
    const float* __restrict__ xin, const float* __restrict__ Wp,
    const float* __restrict__ bp, float* __restrict__ out)
{
    __shared__ float sW[HC * OC];
    const int t = threadIdx.x;
    for (int i = t; i < HC * OC / 4; i += 256)
        reinterpret_cast<float4*>(sW)[i] = reinterpret_cast<const float4*>(Wp)[i];
    __syncthreads();
    const int row = blockIdx.x * 64 + (t >> 2);
    if (row >= NN) return;
    const int c0 = (t & 3) * 16;

    float acc[16];
#pragma unroll
    for (int j = 0; j < 16; ++j) acc[j] = 0.f;

    const float4* xr4 = reinterpret_cast<const float4*>(xin + (size_t)row * HC);
#pragma unroll 4
    for (int k4 = 0; k4 < HC / 4; ++k4) {
        const float4 xv = xr4[k4];
        const float xs[4] = {xv.x, xv.y, xv.z, xv.w};
#pragma unroll
        for (int kk = 0; kk < 4; ++kk) {
            const int k = k4 * 4 + kk;
            const float4* w = reinterpret_cast<const float4*>(sW + k * OC + c0);
#pragma unroll
            for (int jj = 0; jj < 4; ++jj) {
                const float4 wv = w[jj];
                acc[4 * jj + 0] += xs[kk] * wv.x;
                acc[4 * jj + 1] += xs[kk] * wv.y;
                acc[4 * jj + 2] += xs[kk] * wv.z;
                acc[4 * jj + 3] += xs[kk] * wv.w;
            }
        }
    }
    float* op = out + (size_t)row * OC + c0;
#pragma unroll
    for (int jj = 0; jj < 4; ++jj) {
        float4 o;
        o.x = acc[4 * jj + 0] + bp[c0 + 4 * jj + 0];
        o.y = acc[4 * jj + 1] + bp[c0 + 4 * jj + 1];
        o.z = acc[4 * jj + 2] + bp[c0 + 4 * jj + 2];
        o.w = acc[4 * jj + 3] + bp[c0 + 4 * jj + 3];
        reinterpret_cast<float4*>(op)[jj] = o;
    }
}

extern "C" void kernel_launch(void* const* d_in, const int* in_sizes, int n_in,
                              void* d_out, int out_size, void* d_ws, size_t ws_size,
                              hipStream_t stream) {
    const float* x    = (const float*)d_in[0];
    const int*   ei   = (const int*)d_in[1];      // [2,E] int32
    const float* Wg   = (const float*)d_in[2];
    const float* bg   = (const float*)d_in[3];
    const float* Wl   = (const float*)d_in[4];
    const float* bl   = (const float*)d_in[5];
    const float* bn_g = (const float*)d_in[6];
    const float* bn_b = (const float*)d_in[7];
    const float* bn_rm= (const float*)d_in[8];
    const float* bn_rv= (const float*)d_in[9];
    const float* Wp   = (const float*)d_in[10];
    const float* bp   = (const float*)d_in[11];
    float* out = (float*)d_out;

    const int* e_src = ei;
    const int* e_dst = ei + NE;

    // workspace layout
    float* bufA = (float*)d_ws;                  // N*H
    float* bufB = bufA + (size_t)NN * HC;        // N*H
    float* bufH = bufB + (size_t)NN * HC;        // N*H
    float* dinv = bufH + (size_t)NN * HC;        // N
    float* csr_w = dinv + NN;                    // E
    int*   csr_src = (int*)(csr_w + NE);         // E
    int*   cnt    = csr_src + NE;                // N
    int*   offs   = cnt + NN;                    // N
    int*   cursor = offs + NN;                   // N
    int*   partials = cursor + NN;               // NB

    const int nblk = (NN + 255) / 256;
    const int eblk = (NE + 255) / 256;

    // CSR build (every call; deterministic structure)
    init_cnt<<<nblk, 256, 0, stream>>>(cnt);
    count_deg<<<eblk, 256, 0, stream>>>(e_dst, cnt);
    calc_dinv<<<nblk, 256, 0, stream>>>(cnt, dinv);
    scan1<<<NB, 256, 0, stream>>>(cnt, offs, partials);
    scan2<<<1, 64, 0, stream>>>(partials);
    scan3<<<nblk, 256, 0, stream>>>(offs, partials, cursor);
    fill_csr<<<eblk, 256, 0, stream>>>(e_src, e_dst, dinv, offs, cursor, csr_src, csr_w);

    const int gemm_blocks = (NN + 63) / 64;
    const int gat_blocks = (NN + 7) / 8;

    const float* xin = x;
    float* pp[NL] = {bufA, bufB, bufA};
    for (int l = 0; l < NL; ++l) {
        float* xnext = pp[l];
        gemm_dual<<<gemm_blocks, 512, 0, stream>>>(
            xin, Wg + (size_t)l * HC * HC, Wl + (size_t)l * HC * HC,
            bg + (size_t)l * HC, bl + (size_t)l * HC, dinv, bufH, xnext);
        gather_conv_bn<<<gat_blocks, 256, 0, stream>>>(
            csr_src, csr_w, offs, cnt, bufH, xnext,
            bn_g + (size_t)l * HC, bn_b + (size_t)l * HC,
            bn_rm + (size_t)l * HC, bn_rv + (size_t)l * HC);
        xin = xnext;
    }

    gemm_out<<<gemm_blocks, 256, 0, stream>>>(xin, Wp, bp, out);
}

// Round 3
// 476.361 us; speedup vs baseline: 5.1593x; 1.4628x over previous
//
#include <hip/hip_runtime.h>
#include <cstddef>

#define NN 50000
#define NE 800000
#define HC 128
#define OC 64
#define NL 3
#define BN_EPS 1e-5f
#define NB ((NN + 1023) / 1024)   // scan blocks (1024 elems each) = 49

// ---------------- degree / dinv ----------------
__global__ void init_cnt(int* __restrict__ cnt) {
    int i = blockIdx.x * blockDim.x + threadIdx.x;
    if (i < NN) cnt[i] = 0;
}

__global__ void count_deg(const int* __restrict__ dst, int* __restrict__ cnt) {
    int e = blockIdx.x * blockDim.x + threadIdx.x;
    if (e < NE) atomicAdd(&cnt[dst[e]], 1);
}

__global__ void calc_dinv(const int* __restrict__ cnt, float* __restrict__ dinv) {
    int i = blockIdx.x * blockDim.x + threadIdx.x;
    if (i < NN) dinv[i] = rsqrtf((float)(cnt[i] + 1));   // +1 self-loop
}

// ---------------- exclusive scan (3 kernels) ----------------
__global__ __launch_bounds__(256) void scan1(const int* __restrict__ cnt,
                                             int* __restrict__ offs,
                                             int* __restrict__ partials) {
    __shared__ int sm[256];
    const int t = threadIdx.x;
    const int base = blockIdx.x * 1024 + t * 4;
    int c[4];
#pragma unroll
    for (int k = 0; k < 4; ++k) c[k] = (base + k < NN) ? cnt[base + k] : 0;
    int s = c[0] + c[1] + c[2] + c[3];
    sm[t] = s;
    __syncthreads();
    for (int off = 1; off < 256; off <<= 1) {
        int v = (t >= off) ? sm[t - off] : 0;
        __syncthreads();
        sm[t] += v;
        __syncthreads();
    }
    int run = sm[t] - s;   // exclusive
    if (t == 255) partials[blockIdx.x] = sm[255];
#pragma unroll
    for (int k = 0; k < 4; ++k) {
        if (base + k < NN) { offs[base + k] = run; run += c[k]; }
    }
}

__global__ void scan2(int* __restrict__ partials) {
    if (threadIdx.x == 0) {
        int run = 0;
        for (int i = 0; i < NB; ++i) { int v = partials[i]; partials[i] = run; run += v; }
    }
}

__global__ void scan3(int* __restrict__ offs, const int* __restrict__ partials,
                      int* __restrict__ cursor) {
    int i = blockIdx.x * blockDim.x + threadIdx.x;
    if (i < NN) { offs[i] += partials[i >> 10]; cursor[i] = 0; }
}

// ---------------- CSR fill ----------------
__global__ void fill_csr(const int* __restrict__ src, const int* __restrict__ dst,
                         const float* __restrict__ dinv, const int* __restrict__ offs,
                         int* __restrict__ cursor,
                         int* __restrict__ csr_src, float* __restrict__ csr_w) {
    int e = blockIdx.x * blockDim.x + threadIdx.x;
    if (e >= NE) return;
    int s = src[e], d = dst[e];
    int p = offs[d] + atomicAdd(&cursor[d], 1);
    csr_src[p] = s;
    csr_w[p] = dinv[s] * dinv[d];
}

// ---------------- fused dual GEMM, restructured ----------------
// 512 threads, 64 rows/block. Thread (rt = t>>5, cj = t&31) computes
// rows rt*4..rt*4+3, G-cols [4cj..4cj+3], L-cols [4cj..4cj+3].
// Weights staged as concat sW[128][256] = [Wg | Wl]; x-tile sX[64][128].
// Weight reads: 32 unique float4 spanning all 32 banks (pure BW, no waste);
// x reads: 2 unique addrs/instr (broadcast).
__global__ __launch_bounds__(512) void gemm_dual(
    const float* __restrict__ xin,
    const float* __restrict__ Wg, const float* __restrict__ Wl,
    const float* __restrict__ bg, const float* __restrict__ bl,
    const float* __restrict__ dinv,
    float* __restrict__ hbuf, float* __restrict__ xnext)
{
    __shared__ float4 sW4[HC * 64];      // [k][64 f4] = [Wg row | Wl row], 128 KB
    __shared__ float4 sX4[64 * 32];      // [row][32 f4], 32 KB
    const int t = threadIdx.x;
    const int rowBase = blockIdx.x * 64;

    const float4* Wg4 = reinterpret_cast<const float4*>(Wg);
    const float4* Wl4 = reinterpret_cast<const float4*>(Wl);
#pragma unroll
    for (int ii = 0; ii < 8; ++ii) {
        const int i = t + ii * 512;              // 0..4095 over Wg f4s
        const int k = i >> 5, c4 = i & 31;
        sW4[k * 64 + c4] = Wg4[i];
        sW4[k * 64 + 32 + c4] = Wl4[i];
    }
    const float4* X4 = reinterpret_cast<const float4*>(xin);
#pragma unroll
    for (int ii = 0; ii < 4; ++ii) {
        const int i = t + ii * 512;              // 0..2047
        const int row = i >> 5;
        float4 v = {0.f, 0.f, 0.f, 0.f};
        if (rowBase + row < NN) v = X4[(size_t)rowBase * 32 + i];
        sX4[i] = v;
    }
    __syncthreads();

    const int rt = t >> 5;
    const int cj = t & 31;
    const float4* wgp = sW4 + cj;
    const float4* wlp = sW4 + 32 + cj;
    const float4* xp  = sX4 + rt * 4 * 32;

    float accG[4][4], accL[4][4];
#pragma unroll
    for (int r = 0; r < 4; ++r)
#pragma unroll
        for (int c = 0; c < 4; ++c) { accG[r][c] = 0.f; accL[r][c] = 0.f; }

#define FMA_STEP(kk, XS0, XS1, XS2, XS3)                                  \
    {                                                                      \
        const float4 g = wgp[(4 * k4 + kk) * 64];                          \
        const float4 l = wlp[(4 * k4 + kk) * 64];                          \
        const float xs[4] = {XS0, XS1, XS2, XS3};                          \
        _Pragma("unroll")                                                  \
        for (int r = 0; r < 4; ++r) {                                      \
            accG[r][0] += xs[r] * g.x; accG[r][1] += xs[r] * g.y;          \
            accG[r][2] += xs[r] * g.z; accG[r][3] += xs[r] * g.w;          \
            accL[r][0] += xs[r] * l.x; accL[r][1] += xs[r] * l.y;          \
            accL[r][2] += xs[r] * l.z; accL[r][3] += xs[r] * l.w;          \
        }                                                                  \
    }

#pragma unroll 4
    for (int k4 = 0; k4 < 32; ++k4) {
        const float4 x0 = xp[0 * 32 + k4];
        const float4 x1 = xp[1 * 32 + k4];
        const float4 x2 = xp[2 * 32 + k4];
        const float4 x3 = xp[3 * 32 + k4];
        FMA_STEP(0, x0.x, x1.x, x2.x, x3.x)
        FMA_STEP(1, x0.y, x1.y, x2.y, x3.y)
        FMA_STEP(2, x0.z, x1.z, x2.z, x3.z)
        FMA_STEP(3, x0.w, x1.w, x2.w, x3.w)
    }
#undef FMA_STEP

    const float4 bg4 = reinterpret_cast<const float4*>(bg)[cj];
    const float4 bl4 = reinterpret_cast<const float4*>(bl)[cj];
#pragma unroll
    for (int r = 0; r < 4; ++r) {
        const int row = rowBase + rt * 4 + r;
        if (row >= NN) continue;
        const float dv = dinv[row];
        const float selfn = dv * dv;
        float4 h4, xo;
        h4.x = accG[r][0]; h4.y = accG[r][1]; h4.z = accG[r][2]; h4.w = accG[r][3];
        xo.x = accL[r][0] + bl4.x + bg4.x + selfn * h4.x;
        xo.y = accL[r][1] + bl4.y + bg4.y + selfn * h4.y;
        xo.z = accL[r][2] + bl4.z + bg4.z + selfn * h4.z;
        xo.w = accL[r][3] + bl4.w + bg4.w + selfn * h4.w;
        reinterpret_cast<float4*>(hbuf + (size_t)row * HC)[cj] = h4;
        reinterpret_cast<float4*>(xnext + (size_t)row * HC)[cj] = xo;
    }
}

// ---------------- CSR gather + BN + ReLU ----------------
__global__ __launch_bounds__(256) void gather_conv_bn(
    const int* __restrict__ csr_src, const float* __restrict__ csr_w,
    const int* __restrict__ offs, const int* __restrict__ cnt,
    const float* __restrict__ h, float* __restrict__ xio,
    const float* __restrict__ g, const float* __restrict__ bb,
    const float* __restrict__ rm, const float* __restrict__ rv)
{
    const int widx = threadIdx.x >> 6;
    const int lane = threadIdx.x & 63;
    const int half = lane >> 5;
    const int li = lane & 31;
    const int node = blockIdx.x * 8 + widx * 2 + half;
    if (node >= NN) return;
    const int beg = offs[node];
    const int n = cnt[node];

    float4 acc = {0.f, 0.f, 0.f, 0.f};
    int j = 0;
    for (; j + 2 <= n; j += 2) {
        const int s0 = csr_src[beg + j];
        const int s1 = csr_src[beg + j + 1];
        const float w0 = csr_w[beg + j];
        const float w1 = csr_w[beg + j + 1];
        const float4 h0 = reinterpret_cast<const float4*>(h + (size_t)s0 * HC)[li];
        const float4 h1 = reinterpret_cast<const float4*>(h + (size_t)s1 * HC)[li];
        acc.x += w0 * h0.x + w1 * h1.x;
        acc.y += w0 * h0.y + w1 * h1.y;
        acc.z += w0 * h0.z + w1 * h1.z;
        acc.w += w0 * h0.w + w1 * h1.w;
    }
    if (j < n) {
        const int s0 = csr_src[beg + j];
        const float w0 = csr_w[beg + j];
        const float4 h0 = reinterpret_cast<const float4*>(h + (size_t)s0 * HC)[li];
        acc.x += w0 * h0.x;
        acc.y += w0 * h0.y;
        acc.z += w0 * h0.z;
        acc.w += w0 * h0.w;
    }

    float4 xv = reinterpret_cast<float4*>(xio + (size_t)node * HC)[li];
    xv.x += acc.x; xv.y += acc.y; xv.z += acc.z; xv.w += acc.w;

    const float4 gv = reinterpret_cast<const float4*>(g)[li];
    const float4 bv = reinterpret_cast<const float4*>(bb)[li];
    const float4 mv = reinterpret_cast<const float4*>(rm)[li];
    const float4 vv = reinterpret_cast<const float4*>(rv)[li];
    xv.x = fmaxf((xv.x - mv.x) * rsqrtf(vv.x + BN_EPS) * gv.x + bv.x, 0.f);
    xv.y = fmaxf((xv.y - mv.y) * rsqrtf(vv.y + BN_EPS) * gv.y + bv.y, 0.f);
    xv.z = fmaxf((xv.z - mv.z) * rsqrtf(vv.z + BN_EPS) * gv.z + bv.z, 0.f);
    xv.w = fmaxf((xv.w - mv.w) * rsqrtf(vv.w + BN_EPS) * gv.w + bv.w, 0.f);
    reinterpret_cast<float4*>(xio + (size_t)node * HC)[li] = xv;
}

// ---------------- output projection, restructured ----------------
// 256 threads, 64 rows/block. Thread (rt = t>>4, cj = t&15): 4 rows x 4 cols.
__global__ __launch_bounds__(256) void gemm_out(
    const float* __restrict__ xin, const float* __restrict__ Wp,
    const float* __restrict__ bp, float* __restrict__ out)
{
    __shared__ float4 sW4[HC * 16];      // [k][16 f4], 32 KB
    __shared__ float4 sX4[64 * 32];      // 32 KB
    const int t = threadIdx.x;
    const int rowBase = blockIdx.x * 64;

    const float4* Wp4 = reinterpret_cast<const float4*>(Wp);
#pragma unroll
    for (int ii = 0; ii < 8; ++ii) sW4[t + ii * 256] = Wp4[t + ii * 256];
    const float4* X4 = reinterpret_cast<const float4*>(xin);
#pragma unroll
    for (int ii = 0; ii < 8; ++ii) {
        const int i = t + ii * 256;
        const int row = i >> 5;
        float4 v = {0.f, 0.f, 0.f, 0.f};
        if (rowBase + row < NN) v = X4[(size_t)rowBase * 32 + i];
        sX4[i] = v;
    }
    __syncthreads();

    const int rt = t >> 4;
    const int cj = t & 15;
    const float4* wp = sW4 + cj;
    const float4* xp = sX4 + rt * 4 * 32;

    float acc[4][4];
#pragma unroll
    for (int r = 0; r < 4; ++r)
#pragma unroll
        for (int c = 0; c < 4; ++c) acc[r][c] = 0.f;

#define OUT_STEP(kk, XS0, XS1, XS2, XS3)                                   \
    {                                                                       \
        const float4 w = wp[(4 * k4 + kk) * 16];                            \
        const float xs[4] = {XS0, XS1, XS2, XS3};                           \
        _Pragma("unroll")                                                   \
        for (int r = 0; r < 4; ++r) {                                       \
            acc[r][0] += xs[r] * w.x; acc[r][1] += xs[r] * w.y;             \
            acc[r][2] += xs[r] * w.z; acc[r][3] += xs[r] * w.w;             \
        }                                                                   \
    }

#pragma unroll 4
    for (int k4 = 0; k4 < 32; ++k4) {
        const float4 x0 = xp[0 * 32 + k4];
        const float4 x1 = xp[1 * 32 + k4];
        const float4 x2 = xp[2 * 32 + k4];
        const float4 x3 = xp[3 * 32 + k4];
        OUT_STEP(0, x0.x, x1.x, x2.x, x3.x)
        OUT_STEP(1, x0.y, x1.y, x2.y, x3.y)
        OUT_STEP(2, x0.z, x1.z, x2.z, x3.z)
        OUT_STEP(3, x0.w, x1.w, x2.w, x3.w)
    }
#undef OUT_STEP

    const float4 bp4 = reinterpret_cast<const float4*>(bp)[cj];
#pragma unroll
    for (int r = 0; r < 4; ++r) {
        const int row = rowBase + rt * 4 + r;
        if (row >= NN) continue;
        float4 o;
        o.x = acc[r][0] + bp4.x;
        o.y = acc[r][1] + bp4.y;
        o.z = acc[r][2] + bp4.z;
        o.w = acc[r][3] + bp4.w;
        reinterpret_cast<float4*>(out + (size_t)row * OC)[cj] = o;
    }
}

extern "C" void kernel_launch(void* const* d_in, const int* in_sizes, int n_in,
                              void* d_out, int out_size, void* d_ws, size_t ws_size,
                              hipStream_t stream) {
    const float* x    = (const float*)d_in[0];
    const int*   ei   = (const int*)d_in[1];      // [2,E] int32
    const float* Wg   = (const float*)d_in[2];
    const float* bg   = (const float*)d_in[3];
    const float* Wl   = (const float*)d_in[4];
    const float* bl   = (const float*)d_in[5];
    const float* bn_g = (const float*)d_in[6];
    const float* bn_b = (const float*)d_in[7];
    const float* bn_rm= (const float*)d_in[8];
    const float* bn_rv= (const float*)d_in[9];
    const float* Wp   = (const float*)d_in[10];
    const float* bp   = (const float*)d_in[11];
    float* out = (float*)d_out;

    const int* e_src = ei;
    const int* e_dst = ei + NE;

    // workspace layout
    float* bufA = (float*)d_ws;                  // N*H
    float* bufB = bufA + (size_t)NN * HC;        // N*H
    float* bufH = bufB + (size_t)NN * HC;        // N*H
    float* dinv = bufH + (size_t)NN * HC;        // N
    float* csr_w = dinv + NN;                    // E
    int*   csr_src = (int*)(csr_w + NE);         // E
    int*   cnt    = csr_src + NE;                // N
    int*   offs   = cnt + NN;                    // N
    int*   cursor = offs + NN;                   // N
    int*   partials = cursor + NN;               // NB

    const int nblk = (NN + 255) / 256;
    const int eblk = (NE + 255) / 256;

    init_cnt<<<nblk, 256, 0, stream>>>(cnt);
    count_deg<<<eblk, 256, 0, stream>>>(e_dst, cnt);
    calc_dinv<<<nblk, 256, 0, stream>>>(cnt, dinv);
    scan1<<<NB, 256, 0, stream>>>(cnt, offs, partials);
    scan2<<<1, 64, 0, stream>>>(partials);
    scan3<<<nblk, 256, 0, stream>>>(offs, partials, cursor);
    fill_csr<<<eblk, 256, 0, stream>>>(e_src, e_dst, dinv, offs, cursor, csr_src, csr_w);

    const int gemm_blocks = (NN + 63) / 64;
    const int gat_blocks = (NN + 7) / 8;

    const float* xin = x;
    float* pp[NL] = {bufA, bufB, bufA};
    for (int l = 0; l < NL; ++l) {
        float* xnext = pp[l];
        gemm_dual<<<gemm_blocks, 512, 0, stream>>>(
            xin, Wg + (size_t)l * HC * HC, Wl + (size_t)l * HC * HC,
            bg + (size_t)l * HC, bl + (size_t)l * HC, dinv, bufH, xnext);
        gather_conv_bn<<<gat_blocks, 256, 0, stream>>>(
            csr_src, csr_w, offs, cnt, bufH, xnext,
            bn_g + (size_t)l * HC, bn_b + (size_t)l * HC,
            bn_rm + (size_t)l * HC, bn_rv + (size_t)l * HC);
        xin = xnext;
    }

    gemm_out<<<gemm_blocks, 256, 0, stream>>>(xin, Wp, bp, out);
}

// Round 4
// 307.635 us; speedup vs baseline: 7.9890x; 1.5485x over previous
//
#include <hip/hip_runtime.h>
#include <cstddef>

#define NN 50000
#define NPAD 50048            // 782 blocks * 64 rows
#define NE 800000
#define HC 128
#define OC 64
#define NL 3
#define BN_EPS 1e-5f
#define NB ((NN + 1023) / 1024)

typedef _Float16 half8 __attribute__((ext_vector_type(8)));
typedef _Float16 half4 __attribute__((ext_vector_type(4)));
typedef float f32x4 __attribute__((ext_vector_type(4)));

// ---------------- degree / dinv ----------------
__global__ void init_cnt(int* __restrict__ cnt) {
    int i = blockIdx.x * blockDim.x + threadIdx.x;
    if (i < NN) cnt[i] = 0;
}

__global__ void count_deg(const int* __restrict__ dst, int* __restrict__ cnt) {
    int e = blockIdx.x * blockDim.x + threadIdx.x;
    if (e < NE) atomicAdd(&cnt[dst[e]], 1);
}

__global__ void calc_dinv(const int* __restrict__ cnt, float* __restrict__ dinv) {
    int i = blockIdx.x * blockDim.x + threadIdx.x;
    if (i < NN) dinv[i] = rsqrtf((float)(cnt[i] + 1));   // +1 self-loop
}

// ---------------- exclusive scan ----------------
__global__ __launch_bounds__(256) void scan1(const int* __restrict__ cnt,
                                             int* __restrict__ offs,
                                             int* __restrict__ partials) {
    __shared__ int sm[256];
    const int t = threadIdx.x;
    const int base = blockIdx.x * 1024 + t * 4;
    int c[4];
#pragma unroll
    for (int k = 0; k < 4; ++k) c[k] = (base + k < NN) ? cnt[base + k] : 0;
    int s = c[0] + c[1] + c[2] + c[3];
    sm[t] = s;
    __syncthreads();
    for (int off = 1; off < 256; off <<= 1) {
        int v = (t >= off) ? sm[t - off] : 0;
        __syncthreads();
        sm[t] += v;
        __syncthreads();
    }
    int run = sm[t] - s;
    if (t == 255) partials[blockIdx.x] = sm[255];
#pragma unroll
    for (int k = 0; k < 4; ++k) {
        if (base + k < NN) { offs[base + k] = run; run += c[k]; }
    }
}

__global__ void scan2(int* __restrict__ partials) {
    if (threadIdx.x == 0) {
        int run = 0;
        for (int i = 0; i < NB; ++i) { int v = partials[i]; partials[i] = run; run += v; }
    }
}

__global__ void scan3(int* __restrict__ offs, const int* __restrict__ partials,
                      int* __restrict__ cursor) {
    int i = blockIdx.x * blockDim.x + threadIdx.x;
    if (i < NN) { offs[i] += partials[i >> 10]; cursor[i] = 0; }
}

// ---------------- CSR fill ----------------
__global__ void fill_csr(const int* __restrict__ src, const int* __restrict__ dst,
                         const float* __restrict__ dinv, const int* __restrict__ offs,
                         int* __restrict__ cursor,
                         int* __restrict__ csr_src, float* __restrict__ csr_w) {
    int e = blockIdx.x * blockDim.x + threadIdx.x;
    if (e >= NE) return;
    int s = src[e], d = dst[e];
    int p = offs[d] + atomicAdd(&cursor[d], 1);
    csr_src[p] = s;
    csr_w[p] = dinv[s] * dinv[d];
}

// ---------------- param prep: pack weights to MFMA B-frag order (fp16), BN fold ----------------
// B-frag for 16x16x32: lane l, elem j holds W[k][n] with k = ks*32+(l>>4)*8+j, n = n4*16+(l&15).
// Frag index: (n4*4+ks)*64+lane, 8 fp16 each.
__global__ void pack_params(const float* __restrict__ Wg, const float* __restrict__ Wl,
                            const float* __restrict__ Wp,
                            const float* __restrict__ bg, const float* __restrict__ bl,
                            const float* __restrict__ bn_g, const float* __restrict__ bn_b,
                            const float* __restrict__ bn_rm, const float* __restrict__ bn_rv,
                            _Float16* __restrict__ wgl16,   // [3][2][2048][8]
                            _Float16* __restrict__ wpp16,   // [1024][8]
                            float* __restrict__ bsum,       // [3][128] bg+bl
                            float* __restrict__ bnsc, float* __restrict__ bnsh) // [3][128]
{
    const int tid = blockIdx.x * blockDim.x + threadIdx.x;
    if (tid < 12288) {
        const int layer = tid >> 12;
        const int gl = (tid >> 11) & 1;
        const int rem = tid & 2047;
        const int lane = rem & 63;
        const int ks = (rem >> 6) & 3;
        const int n4 = rem >> 8;
        const float* W = (gl ? Wl : Wg) + (size_t)layer * HC * HC;
        const int kbase = ks * 32 + (lane >> 4) * 8;
        const int n = n4 * 16 + (lane & 15);
        _Float16* dst = wgl16 + (size_t)tid * 8;
#pragma unroll
        for (int j = 0; j < 8; ++j) dst[j] = (_Float16)W[(size_t)(kbase + j) * HC + n];
    } else if (tid < 13312) {
        const int f = tid - 12288;
        const int lane = f & 63;
        const int ks = (f >> 6) & 3;
        const int n4 = f >> 8;
        const int kbase = ks * 32 + (lane >> 4) * 8;
        const int n = n4 * 16 + (lane & 15);
        _Float16* dst = wpp16 + (size_t)f * 8;
#pragma unroll
        for (int j = 0; j < 8; ++j) dst[j] = (_Float16)Wp[(size_t)(kbase + j) * OC + n];
    } else if (tid < 13312 + NL * HC) {
        const int i = tid - 13312;
        bsum[i] = bg[i] + bl[i];
        const float sc = bn_g[i] * rsqrtf(bn_rv[i] + BN_EPS);
        bnsc[i] = sc;
        bnsh[i] = bn_b[i] - bn_rm[i] * sc;
    }
}

// ---------------- x fp32 -> fp16 ----------------
__global__ void conv_x16(const float* __restrict__ x, _Float16* __restrict__ x16) {
    const int i = blockIdx.x * blockDim.x + threadIdx.x;
    if (i >= NN * HC / 4) return;
    const float4 v = reinterpret_cast<const float4*>(x)[i];
    half4 o = {(_Float16)v.x, (_Float16)v.y, (_Float16)v.z, (_Float16)v.w};
    reinterpret_cast<half4*>(x16)[i] = o;
}

// ---------------- dual GEMM via MFMA: h16 = x@Wg, acc32 = x@Wl + bsum + selfn*h ----------------
// 256 threads = 4 waves; wave handles 16 rows x 128 cols for both G and L.
// No LDS, no barriers. B-frags direct from L2 (packed), A-frags from row-major x16.
__global__ __launch_bounds__(256) void gemm_dual_mfma(
    const _Float16* __restrict__ x16,
    const _Float16* __restrict__ Wgp, const _Float16* __restrict__ Wlp,
    const float* __restrict__ bsum, const float* __restrict__ dinv,
    _Float16* __restrict__ h16, float* __restrict__ acc32)
{
    const int wave = threadIdx.x >> 6;
    const int lane = threadIdx.x & 63;
    const int rowBase = blockIdx.x * 64 + wave * 16;
    const int ar = rowBase + (lane & 15);
    const int ak = (lane >> 4) * 8;

    half8 a[4];
#pragma unroll
    for (int ks = 0; ks < 4; ++ks)
        a[ks] = *reinterpret_cast<const half8*>(x16 + (size_t)ar * HC + ks * 32 + ak);

    f32x4 accG[8], accL[8];
#pragma unroll
    for (int n4 = 0; n4 < 8; ++n4) { accG[n4] = (f32x4)0.f; accL[n4] = (f32x4)0.f; }

    const half8* wg = reinterpret_cast<const half8*>(Wgp) + lane;
    const half8* wl = reinterpret_cast<const half8*>(Wlp) + lane;
#pragma unroll
    for (int n4 = 0; n4 < 8; ++n4) {
#pragma unroll
        for (int ks = 0; ks < 4; ++ks) {
            const half8 bG = wg[(n4 * 4 + ks) * 64];
            accG[n4] = __builtin_amdgcn_mfma_f32_16x16x32_f16(a[ks], bG, accG[n4], 0, 0, 0);
            const half8 bL = wl[(n4 * 4 + ks) * 64];
            accL[n4] = __builtin_amdgcn_mfma_f32_16x16x32_f16(a[ks], bL, accL[n4], 0, 0, 0);
        }
    }

    const int col = lane & 15;
    const int roff = (lane >> 4) * 4;
#pragma unroll
    for (int r = 0; r < 4; ++r) {
        const int row = rowBase + roff + r;
        if (row >= NN) continue;
        const float dv = dinv[row];
        const float selfn = dv * dv;
        _Float16* hp = h16 + (size_t)row * HC + col;
        float* xp = acc32 + (size_t)row * HC + col;
#pragma unroll
        for (int n4 = 0; n4 < 8; ++n4) {
            const float hval = accG[n4][r];
            hp[n4 * 16] = (_Float16)hval;
            xp[n4 * 16] = accL[n4][r] + bsum[n4 * 16 + col] + selfn * hval;
        }
    }
}

// ---------------- CSR gather (fp16 h) + BN + ReLU -> fp16 x ----------------
__global__ __launch_bounds__(256) void gather_conv_bn(
    const int* __restrict__ csr_src, const float* __restrict__ csr_w,
    const int* __restrict__ offs, const int* __restrict__ cnt,
    const _Float16* __restrict__ h16, const float* __restrict__ acc32,
    _Float16* __restrict__ xout16,
    const float* __restrict__ bnsc, const float* __restrict__ bnsh)
{
    const int widx = threadIdx.x >> 6;
    const int lane = threadIdx.x & 63;
    const int half = lane >> 5;
    const int li = lane & 31;
    const int node = blockIdx.x * 8 + widx * 2 + half;
    if (node >= NN) return;
    const int beg = offs[node];
    const int n = cnt[node];

    float acc0 = 0.f, acc1 = 0.f, acc2 = 0.f, acc3 = 0.f;
    int j = 0;
    for (; j + 2 <= n; j += 2) {
        const int s0 = csr_src[beg + j];
        const int s1 = csr_src[beg + j + 1];
        const float w0 = csr_w[beg + j];
        const float w1 = csr_w[beg + j + 1];
        const half4 h0 = reinterpret_cast<const half4*>(h16 + (size_t)s0 * HC)[li];
        const half4 h1 = reinterpret_cast<const half4*>(h16 + (size_t)s1 * HC)[li];
        acc0 += w0 * (float)h0[0] + w1 * (float)h1[0];
        acc1 += w0 * (float)h0[1] + w1 * (float)h1[1];
        acc2 += w0 * (float)h0[2] + w1 * (float)h1[2];
        acc3 += w0 * (float)h0[3] + w1 * (float)h1[3];
    }
    if (j < n) {
        const int s0 = csr_src[beg + j];
        const float w0 = csr_w[beg + j];
        const half4 h0 = reinterpret_cast<const half4*>(h16 + (size_t)s0 * HC)[li];
        acc0 += w0 * (float)h0[0];
        acc1 += w0 * (float)h0[1];
        acc2 += w0 * (float)h0[2];
        acc3 += w0 * (float)h0[3];
    }

    const float4 xv = reinterpret_cast<const float4*>(acc32 + (size_t)node * HC)[li];
    const float4 sc = reinterpret_cast<const float4*>(bnsc)[li];
    const float4 sh = reinterpret_cast<const float4*>(bnsh)[li];
    half4 o;
    o[0] = (_Float16)fmaxf((xv.x + acc0) * sc.x + sh.x, 0.f);
    o[1] = (_Float16)fmaxf((xv.y + acc1) * sc.y + sh.y, 0.f);
    o[2] = (_Float16)fmaxf((xv.z + acc2) * sc.z + sh.z, 0.f);
    o[3] = (_Float16)fmaxf((xv.w + acc3) * sc.w + sh.w, 0.f);
    reinterpret_cast<half4*>(xout16 + (size_t)node * HC)[li] = o;
}

// ---------------- output projection via MFMA ----------------
__global__ __launch_bounds__(256) void gemm_out_mfma(
    const _Float16* __restrict__ x16, const _Float16* __restrict__ Wpp,
    const float* __restrict__ bp, float* __restrict__ out)
{
    const int wave = threadIdx.x >> 6;
    const int lane = threadIdx.x & 63;
    const int rowBase = blockIdx.x * 64 + wave * 16;
    const int ar = rowBase + (lane & 15);
    const int ak = (lane >> 4) * 8;

    half8 a[4];
#pragma unroll
    for (int ks = 0; ks < 4; ++ks)
        a[ks] = *reinterpret_cast<const half8*>(x16 + (size_t)ar * HC + ks * 32 + ak);

    f32x4 acc[4];
#pragma unroll
    for (int n4 = 0; n4 < 4; ++n4) acc[n4] = (f32x4)0.f;

    const half8* wp = reinterpret_cast<const half8*>(Wpp) + lane;
#pragma unroll
    for (int n4 = 0; n4 < 4; ++n4)
#pragma unroll
        for (int ks = 0; ks < 4; ++ks)
            acc[n4] = __builtin_amdgcn_mfma_f32_16x16x32_f16(a[ks], wp[(n4 * 4 + ks) * 64], acc[n4], 0, 0, 0);

    const int col = lane & 15;
    const int roff = (lane >> 4) * 4;
#pragma unroll
    for (int r = 0; r < 4; ++r) {
        const int row = rowBase + roff + r;
        if (row >= NN) continue;
        float* op = out + (size_t)row * OC + col;
#pragma unroll
        for (int n4 = 0; n4 < 4; ++n4)
            op[n4 * 16] = acc[n4][r] + bp[n4 * 16 + col];
    }
}

extern "C" void kernel_launch(void* const* d_in, const int* in_sizes, int n_in,
                              void* d_out, int out_size, void* d_ws, size_t ws_size,
                              hipStream_t stream) {
    const float* x    = (const float*)d_in[0];
    const int*   ei   = (const int*)d_in[1];
    const float* Wg   = (const float*)d_in[2];
    const float* bg   = (const float*)d_in[3];
    const float* Wl   = (const float*)d_in[4];
    const float* bl   = (const float*)d_in[5];
    const float* bn_g = (const float*)d_in[6];
    const float* bn_b = (const float*)d_in[7];
    const float* bn_rm= (const float*)d_in[8];
    const float* bn_rv= (const float*)d_in[9];
    const float* Wp   = (const float*)d_in[10];
    const float* bp   = (const float*)d_in[11];
    float* out = (float*)d_out;

    const int* e_src = ei;
    const int* e_dst = ei + NE;

    // workspace layout
    char* p = (char*)d_ws;
    _Float16* x16a = (_Float16*)p;            p += (size_t)NPAD * HC * 2;
    _Float16* x16b = (_Float16*)p;            p += (size_t)NPAD * HC * 2;
    _Float16* h16  = (_Float16*)p;            p += (size_t)NPAD * HC * 2;
    float* acc32   = (float*)p;               p += (size_t)NPAD * HC * 4;
    float* dinv    = (float*)p;               p += (size_t)NN * 4;
    float* csr_w   = (float*)p;               p += (size_t)NE * 4;
    int* csr_src   = (int*)p;                 p += (size_t)NE * 4;
    int* cnt       = (int*)p;                 p += (size_t)NN * 4;
    int* offs      = (int*)p;                 p += (size_t)NN * 4;
    int* cursor    = (int*)p;                 p += (size_t)NN * 4;
    int* partials  = (int*)p;                 p += (size_t)NB * 4 + 64;
    _Float16* wgl16 = (_Float16*)p;           p += (size_t)12288 * 8 * 2;
    _Float16* wpp16 = (_Float16*)p;           p += (size_t)1024 * 8 * 2;
    float* bsum    = (float*)p;               p += (size_t)NL * HC * 4;
    float* bnsc    = (float*)p;               p += (size_t)NL * HC * 4;
    float* bnsh    = (float*)p;               p += (size_t)NL * HC * 4;

    const int nblk = (NN + 255) / 256;
    const int eblk = (NE + 255) / 256;

    init_cnt<<<nblk, 256, 0, stream>>>(cnt);
    count_deg<<<eblk, 256, 0, stream>>>(e_dst, cnt);
    calc_dinv<<<nblk, 256, 0, stream>>>(cnt, dinv);
    scan1<<<NB, 256, 0, stream>>>(cnt, offs, partials);
    scan2<<<1, 64, 0, stream>>>(partials);
    scan3<<<nblk, 256, 0, stream>>>(offs, partials, cursor);
    fill_csr<<<eblk, 256, 0, stream>>>(e_src, e_dst, dinv, offs, cursor, csr_src, csr_w);

    pack_params<<<(13312 + NL * HC + 255) / 256, 256, 0, stream>>>(
        Wg, Wl, Wp, bg, bl, bn_g, bn_b, bn_rm, bn_rv,
        wgl16, wpp16, bsum, bnsc, bnsh);
    conv_x16<<<(NN * HC / 4 + 255) / 256, 256, 0, stream>>>(x, x16a);

    const int gemm_blocks = NPAD / 64;       // 782
    const int gat_blocks = (NN + 7) / 8;

    _Float16* xin16 = x16a;
    _Float16* pp16[NL] = {x16b, x16a, x16b};
    for (int l = 0; l < NL; ++l) {
        _Float16* xnext16 = pp16[l];
        gemm_dual_mfma<<<gemm_blocks, 256, 0, stream>>>(
            xin16,
            wgl16 + (size_t)(l * 2 + 0) * 2048 * 8,
            wgl16 + (size_t)(l * 2 + 1) * 2048 * 8,
            bsum + (size_t)l * HC, dinv, h16, acc32);
        gather_conv_bn<<<gat_blocks, 256, 0, stream>>>(
            csr_src, csr_w, offs, cnt, h16, acc32, xnext16,
            bnsc + (size_t)l * HC, bnsh + (size_t)l * HC);
        xin16 = xnext16;
    }

    gemm_out_mfma<<<gemm_blocks, 256, 0, stream>>>(xin16, wpp16, bp, out);
}